// Round 10
// baseline (132.693 us; speedup 1.0000x reference)
//
#include <hip/hip_runtime.h>
#include <cstdint>
#include <cstddef>

// Problem constants (fixed by the reference)
#define NB 8
#define NA 100000
#define NM 32
#define NC 80
#define BLK 512
#define NBLK ((NA + BLK - 1) / BLK)   // 196 blocks per image
#define NTILE (NB * NBLK)             // 1568 blocks total
#define LN2F 0.69314718056f

// BLK = 25*20 + 12  (incremental div/mod-20 stepping in the streaming loop)
#define ALQ 25
#define ALR 12

// clang-native float4 (required by __builtin_nontemporal_load)
typedef float nfloat4 __attribute__((ext_vector_type(4)));

// ws layout:
//   offset 0:    unsigned counter           (memset to 0 each call)
//   offset 256:  float4 parts[NTILE]        (every block writes its slot)

__device__ __forceinline__ float neg_term(const nfloat4 v) {
    // sum over 4 classes of p^2 * log2(1-p)   (negative)
    const float p0 = __builtin_amdgcn_fmed3f(v.x, 1e-4f, 0.9999f);
    float g = p0 * p0 * __log2f(1.f - p0);
    const float p1 = __builtin_amdgcn_fmed3f(v.y, 1e-4f, 0.9999f);
    g = __fmaf_rn(p1 * p1, __log2f(1.f - p1), g);
    const float p2 = __builtin_amdgcn_fmed3f(v.z, 1e-4f, 0.9999f);
    g = __fmaf_rn(p2 * p2, __log2f(1.f - p2), g);
    const float p3 = __builtin_amdgcn_fmed3f(v.w, 1e-4f, 0.9999f);
    g = __fmaf_rn(p3 * p3, __log2f(1.f - p3), g);
    return g;
}

__global__ __launch_bounds__(512) void fused_kernel(
    const float* __restrict__ cls,       // [NB,NA,NC]
    const float* __restrict__ regs,      // [NB,NA,4]
    const float* __restrict__ anchors,   // [NA,4]
    const float* __restrict__ annots,    // [NB,NM,5]
    float4* __restrict__ parts,          // [NTILE]
    unsigned* __restrict__ counter,
    float* __restrict__ out)             // [2]
{
    const int b   = blockIdx.y;
    const int blk = blockIdx.x;
    const int tid = threadIdx.x;
    const int a   = blk * BLK + tid;

    __shared__ float sann[NM * 5];
    __shared__ float sw[BLK];            // per-anchor negative-term weight (0 or 0.75)
    __shared__ float sred[8 * 3];
    __shared__ float simg[NB * 2];
    __shared__ bool  slast;

    if (tid < NM * 5) sann[tid] = annots[b * NM * 5 + tid];
    __syncthreads();

    // ---- Phase 1: assignment, regression loss, positive-target correction ----
    float reg_acc = 0.f;
    float posf    = 0.f;
    float corr    = 0.f;
    int   st      = 201;   // 0..79 pos class, 200 neg, 201 ignore

    if (a < NA) {
        const float4 av = reinterpret_cast<const float4*>(anchors)[a];
        const float ax1 = av.x, ay1 = av.y, ax2 = av.z, ay2 = av.w;
        const float aw = ax2 - ax1, ah = ay2 - ay1;
        const float aarea = aw * ah;

        float best = -1e30f;
        int   barg = 0;
        #pragma unroll
        for (int m = 0; m < NM; ++m) {
            const float bx1 = sann[m * 5 + 0];
            const float by1 = sann[m * 5 + 1];
            const float bx2 = sann[m * 5 + 2];
            const float by2 = sann[m * 5 + 3];
            const float bc  = sann[m * 5 + 4];
            const float area = (bx2 - bx1) * (by2 - by1);
            float iw = fminf(ax2, bx2) - fmaxf(ax1, bx1);
            float ih = fminf(ay2, by2) - fmaxf(ay1, by1);
            iw = fmaxf(iw, 0.f);
            ih = fmaxf(ih, 0.f);
            const float inter = iw * ih;
            const float ua = fmaxf(aarea + area - inter, 1e-8f);
            float iou = inter * __builtin_amdgcn_rcpf(ua);   // feeds thresholds/argmax only
            if (bc == -1.0f) iou = -1.0f;                    // mask padded annotations
            if (iou > best) { best = iou; barg = m; }        // first-max == jnp.argmax
        }

        if (best >= 0.5f) {
            const float bx1 = sann[barg * 5 + 0];
            const float by1 = sann[barg * 5 + 1];
            const float bx2 = sann[barg * 5 + 2];
            const float by2 = sann[barg * 5 + 3];
            st   = (int)sann[barg * 5 + 4];
            posf = 1.f;
            const float gw  = fmaxf(bx2 - bx1, 0.f);
            const float gh  = fmaxf(by2 - by1, 0.f);
            const float gcx = bx1 + 0.5f * (bx2 - bx1);
            const float gcy = by1 + 0.5f * (by2 - by1);
            const float acx = ax1 + 0.5f * aw;
            const float acy = ay1 + 0.5f * ah;
            const float t0 = ((gcx - acx) / aw) * 10.f;
            const float t1 = ((gcy - acy) / ah) * 10.f;
            const float t2 = __logf(gw / aw) * 5.f;
            const float t3 = __logf(gh / ah) * 5.f;
            const float4 rp = reinterpret_cast<const float4*>(regs)[(size_t)b * NA + a];
            const float d0 = fabsf(t0 - rp.x);
            const float d1 = fabsf(t1 - rp.y);
            const float d2 = fabsf(t2 - rp.z);
            const float d3 = fabsf(t3 - rp.w);
            const float TH = 1.f / 9.f;
            const float C59 = 5.f / 9.f;
            reg_acc  = (d0 <= TH) ? 4.5f * d0 * d0 : d0 - C59;
            reg_acc += (d1 <= TH) ? 4.5f * d1 * d1 : d1 - C59;
            reg_acc += (d2 <= TH) ? 4.5f * d2 * d2 : d2 - C59;
            reg_acc += (d3 <= TH) ? 4.5f * d3 * d3 : d3 - C59;
            // focal correction at the single target element:
            //   +0.25*(1-pt)^2*(-log pt) - 0.75*pt^2*(-log(1-pt))
            const float pr  = cls[((size_t)b * NA + a) * NC + st];
            const float pt  = __builtin_amdgcn_fmed3f(pr, 1e-4f, 0.9999f);
            const float omt = 1.f - pt;
            corr = -0.25f * omt * omt * __logf(pt) + 0.75f * (pt * pt) * __logf(omt);
        } else if (best < 0.4f) {
            st = 200;
        }
    }
    sw[tid] = (st == 201) ? 0.f : 0.75f;   // a>=NA stays 201 -> weight 0
    __syncthreads();

    // ---- Phase 2: streaming focal scan with non-temporal loads ----
    const int na_blk = min(BLK, NA - blk * BLK);
    const nfloat4* __restrict__ p4 =
        reinterpret_cast<const nfloat4*>(cls) + ((size_t)b * NA + (size_t)blk * BLK) * (NC / 4);

    float sneg = 0.f;                    // sum w * p^2 * log2(1-p)  (negative)
    int al  = tid / 20;                  // anchor of element i = k*BLK+tid
    int rem = tid - al * 20;

    if (na_blk == BLK) {                 // hot path: 195 of 196 blocks per image
        #pragma unroll 5
        for (int k = 0; k < 20; ++k) {
            const nfloat4 v = __builtin_nontemporal_load(p4 + k * BLK + tid);
            const float wgt = sw[al];
            sneg = __fmaf_rn(wgt, neg_term(v), sneg);
            rem += ALR;
            const int c = (rem >= 20) ? 1 : 0;
            al  += ALQ + c;
            rem -= c * 20;
        }
    } else {                             // tail block: clamp + masked weight
        const int n4 = na_blk * (NC / 4);
        #pragma unroll 5
        for (int k = 0; k < 20; ++k) {
            const int i = k * BLK + tid;
            const nfloat4 v = __builtin_nontemporal_load(p4 + min(i, n4 - 1));
            const float wgt = (i < n4) ? sw[al] : 0.f;
            sneg = __fmaf_rn(wgt, neg_term(v), sneg);
            rem += ALR;
            const int c = (rem >= 20) ? 1 : 0;
            al  += ALQ + c;
            rem -= c * 20;
        }
    }

    float cacc = __fmaf_rn(-LN2F, sneg, corr);

    // ---- Phase 3: block reduction, one float4 store per block ----
    float r = reg_acc;
    float p = posf;
    #pragma unroll
    for (int off = 32; off; off >>= 1) {
        cacc += __shfl_down(cacc, off);
        r    += __shfl_down(r, off);
        p    += __shfl_down(p, off);
    }
    const int w = tid >> 6;
    if ((tid & 63) == 0) {
        sred[w * 3 + 0] = cacc;
        sred[w * 3 + 1] = r;
        sred[w * 3 + 2] = p;
    }
    __syncthreads();

    // ---- Phase 4: done-counter handoff. ONLY tid 0 fences (R5 lesson:
    // an all-thread device fence = ~800k L2 writebacks = 10x regression;
    // release ordering needs only the storing thread's fence).
    if (tid == 0) {
        float C = 0.f, R = 0.f, P = 0.f;
        #pragma unroll
        for (int i = 0; i < 8; ++i) {
            C += sred[i * 3 + 0];
            R += sred[i * 3 + 1];
            P += sred[i * 3 + 2];
        }
        parts[b * NBLK + blk] = make_float4(C, R, P, 0.f);
        __threadfence();                             // release my parts store
        const unsigned prev = atomicAdd(counter, 1u);
        slast = (prev == (unsigned)(NTILE - 1));
    }
    __syncthreads();
    if (!slast) return;

    // ---- Phase 5: last block reduces all partials and writes out ----
    __threadfence();                                 // acquire remote parts
    const int lane = tid & 63;
    const int bi   = tid >> 6;                       // 8 waves, one image each
    float C = 0.f, R = 0.f, P = 0.f;
    for (int i = lane; i < NBLK; i += 64) {
        const float4 v = parts[bi * NBLK + i];
        C += v.x; R += v.y; P += v.z;
    }
    #pragma unroll
    for (int off = 32; off; off >>= 1) {
        C += __shfl_down(C, off);
        R += __shfl_down(R, off);
        P += __shfl_down(P, off);
    }
    const bool vld = (lane < NM) && (annots[bi * NM * 5 + lane * 5 + 4] != -1.0f);
    const unsigned long long mball = __ballot(vld);
    if (lane == 0) {
        const bool hv = (mball != 0ULL);
        const float d = fmaxf(P, 1.f);
        simg[bi * 2 + 0] = hv ? C / d : 0.f;
        simg[bi * 2 + 1] = (P > 0.f) ? R / (4.f * d) : 0.f;
    }
    __syncthreads();
    if (tid == 0) {
        float cm = 0.f, rm = 0.f;
        #pragma unroll
        for (int i = 0; i < NB; ++i) {
            cm += simg[i * 2 + 0];
            rm += simg[i * 2 + 1];
        }
        out[0] = cm * (1.f / NB);
        out[1] = rm * (1.f / NB);
    }
}

extern "C" void kernel_launch(void* const* d_in, const int* in_sizes, int n_in,
                              void* d_out, int out_size, void* d_ws, size_t ws_size,
                              hipStream_t stream) {
    const float* cls     = (const float*)d_in[0];  // [NB,NA,NC]
    const float* regs    = (const float*)d_in[1];  // [NB,NA,4]
    const float* anchors = (const float*)d_in[2];  // [1,NA,4]
    const float* annots  = (const float*)d_in[3];  // [NB,NM,5]
    float* out = (float*)d_out;

    unsigned* counter = (unsigned*)d_ws;
    float4*   parts   = (float4*)((char*)d_ws + 256);  // 25 KB, fully overwritten

    hipMemsetAsync(d_ws, 0, 4, stream);  // re-arm done-counter (capture-legal)

    dim3 g1(NBLK, NB);                   // 1568 blocks
    fused_kernel<<<g1, BLK, 0, stream>>>(cls, regs, anchors, annots, parts, counter, out);
}

// Round 11
// 49.304 us; speedup vs baseline: 2.6914x; 2.6914x over previous
//
#include <hip/hip_runtime.h>
#include <cstdint>
#include <cstddef>

// Problem constants (fixed by the reference)
#define NB 8
#define NA 100000
#define NM 32
#define NC 80
#define BLK 512
#define NBLK ((NA + BLK - 1) / BLK)   // 196 blocks per image
#define LN2F 0.69314718056f

// BLK = 25*20 + 12  (incremental div/mod-20 stepping in the streaming loop)
#define ALQ 25
#define ALR 12

// clang-native float4 (required by __builtin_nontemporal_load)
typedef float nfloat4 __attribute__((ext_vector_type(4)));

// ws layout: float4 parts[NB][NBLK]; every block writes its slot -> no init needed.

__device__ __forceinline__ float neg_term(const nfloat4 v) {
    // sum over 4 classes of p^2 * log2(1-p)   (negative)
    const float p0 = __builtin_amdgcn_fmed3f(v.x, 1e-4f, 0.9999f);
    float g = p0 * p0 * __log2f(1.f - p0);
    const float p1 = __builtin_amdgcn_fmed3f(v.y, 1e-4f, 0.9999f);
    g = __fmaf_rn(p1 * p1, __log2f(1.f - p1), g);
    const float p2 = __builtin_amdgcn_fmed3f(v.z, 1e-4f, 0.9999f);
    g = __fmaf_rn(p2 * p2, __log2f(1.f - p2), g);
    const float p3 = __builtin_amdgcn_fmed3f(v.w, 1e-4f, 0.9999f);
    g = __fmaf_rn(p3 * p3, __log2f(1.f - p3), g);
    return g;
}

__global__ __launch_bounds__(512) void fused_kernel(
    const float* __restrict__ cls,       // [NB,NA,NC]
    const float* __restrict__ regs,      // [NB,NA,4]
    const float* __restrict__ anchors,   // [NA,4]
    const float* __restrict__ annots,    // [NB,NM,5]
    float4* __restrict__ parts)          // [NB*NBLK]
{
    const int b   = blockIdx.y;
    const int blk = blockIdx.x;
    const int tid = threadIdx.x;
    const int a   = blk * BLK + tid;

    __shared__ float sann[NM * 5];
    __shared__ float sw[BLK];            // per-anchor negative-term weight (0 or 0.75)
    __shared__ float sred[8 * 3];

    if (tid < NM * 5) sann[tid] = annots[b * NM * 5 + tid];
    __syncthreads();

    // ---- Phase 1: assignment, regression loss, positive-target correction ----
    float reg_acc = 0.f;
    float posf    = 0.f;
    float corr    = 0.f;
    int   st      = 201;   // 0..79 pos class, 200 neg, 201 ignore

    if (a < NA) {
        const float4 av = reinterpret_cast<const float4*>(anchors)[a];
        const float ax1 = av.x, ay1 = av.y, ax2 = av.z, ay2 = av.w;
        const float aw = ax2 - ax1, ah = ay2 - ay1;
        const float aarea = aw * ah;

        float best = -1e30f;
        int   barg = 0;
        #pragma unroll
        for (int m = 0; m < NM; ++m) {
            const float bx1 = sann[m * 5 + 0];
            const float by1 = sann[m * 5 + 1];
            const float bx2 = sann[m * 5 + 2];
            const float by2 = sann[m * 5 + 3];
            const float bc  = sann[m * 5 + 4];
            const float area = (bx2 - bx1) * (by2 - by1);
            float iw = fminf(ax2, bx2) - fmaxf(ax1, bx1);
            float ih = fminf(ay2, by2) - fmaxf(ay1, by1);
            iw = fmaxf(iw, 0.f);
            ih = fmaxf(ih, 0.f);
            const float inter = iw * ih;
            const float ua = fmaxf(aarea + area - inter, 1e-8f);
            float iou = inter * __builtin_amdgcn_rcpf(ua);   // feeds thresholds/argmax only
            if (bc == -1.0f) iou = -1.0f;                    // mask padded annotations
            if (iou > best) { best = iou; barg = m; }        // first-max == jnp.argmax
        }

        if (best >= 0.5f) {
            const float bx1 = sann[barg * 5 + 0];
            const float by1 = sann[barg * 5 + 1];
            const float bx2 = sann[barg * 5 + 2];
            const float by2 = sann[barg * 5 + 3];
            st   = (int)sann[barg * 5 + 4];
            posf = 1.f;
            const float gw  = fmaxf(bx2 - bx1, 0.f);
            const float gh  = fmaxf(by2 - by1, 0.f);
            const float gcx = bx1 + 0.5f * (bx2 - bx1);
            const float gcy = by1 + 0.5f * (by2 - by1);
            const float acx = ax1 + 0.5f * aw;
            const float acy = ay1 + 0.5f * ah;
            const float t0 = ((gcx - acx) / aw) * 10.f;
            const float t1 = ((gcy - acy) / ah) * 10.f;
            const float t2 = __logf(gw / aw) * 5.f;
            const float t3 = __logf(gh / ah) * 5.f;
            const float4 rp = reinterpret_cast<const float4*>(regs)[(size_t)b * NA + a];
            const float d0 = fabsf(t0 - rp.x);
            const float d1 = fabsf(t1 - rp.y);
            const float d2 = fabsf(t2 - rp.z);
            const float d3 = fabsf(t3 - rp.w);
            const float TH = 1.f / 9.f;
            const float C59 = 5.f / 9.f;
            reg_acc  = (d0 <= TH) ? 4.5f * d0 * d0 : d0 - C59;
            reg_acc += (d1 <= TH) ? 4.5f * d1 * d1 : d1 - C59;
            reg_acc += (d2 <= TH) ? 4.5f * d2 * d2 : d2 - C59;
            reg_acc += (d3 <= TH) ? 4.5f * d3 * d3 : d3 - C59;
            // focal correction at the single target element:
            //   +0.25*(1-pt)^2*(-log pt) - 0.75*pt^2*(-log(1-pt))
            const float pr  = cls[((size_t)b * NA + a) * NC + st];
            const float pt  = __builtin_amdgcn_fmed3f(pr, 1e-4f, 0.9999f);
            const float omt = 1.f - pt;
            corr = -0.25f * omt * omt * __logf(pt) + 0.75f * (pt * pt) * __logf(omt);
        } else if (best < 0.4f) {
            st = 200;
        }
    }
    sw[tid] = (st == 201) ? 0.f : 0.75f;   // a>=NA stays 201 -> weight 0
    __syncthreads();

    // ---- Phase 2: streaming focal scan with non-temporal loads ----
    // Read-once stream: nt skips L2 allocation (L2 is 4 MiB/XCD, stream is
    // 256 MB -> allocation is pure pollution on the L3->CU path).
    const int na_blk = min(BLK, NA - blk * BLK);
    const nfloat4* __restrict__ p4 =
        reinterpret_cast<const nfloat4*>(cls) + ((size_t)b * NA + (size_t)blk * BLK) * (NC / 4);

    float sneg = 0.f;                    // sum w * p^2 * log2(1-p)  (negative)
    int al  = tid / 20;                  // anchor of element i = k*BLK+tid
    int rem = tid - al * 20;

    if (na_blk == BLK) {                 // hot path: 195 of 196 blocks per image
        #pragma unroll 5
        for (int k = 0; k < 20; ++k) {
            const nfloat4 v = __builtin_nontemporal_load(p4 + k * BLK + tid);
            const float wgt = sw[al];
            sneg = __fmaf_rn(wgt, neg_term(v), sneg);
            // incremental al = (i+BLK)/20, rem = (i+BLK)%20
            rem += ALR;
            const int c = (rem >= 20) ? 1 : 0;
            al  += ALQ + c;
            rem -= c * 20;
        }
    } else {                             // tail block: clamp + masked weight
        const int n4 = na_blk * (NC / 4);
        #pragma unroll 5
        for (int k = 0; k < 20; ++k) {
            const int i = k * BLK + tid;
            const nfloat4 v = __builtin_nontemporal_load(p4 + min(i, n4 - 1));
            const float wgt = (i < n4) ? sw[al] : 0.f;
            sneg = __fmaf_rn(wgt, neg_term(v), sneg);
            rem += ALR;
            const int c = (rem >= 20) ? 1 : 0;
            al  += ALQ + c;
            rem -= c * 20;
        }
    }

    float cacc = __fmaf_rn(-LN2F, sneg, corr);

    // ---- Phase 3: block reduction, one float4 store per block ----
    float r = reg_acc;
    float p = posf;
    #pragma unroll
    for (int off = 32; off; off >>= 1) {
        cacc += __shfl_down(cacc, off);
        r    += __shfl_down(r, off);
        p    += __shfl_down(p, off);
    }
    const int w = tid >> 6;
    if ((tid & 63) == 0) {
        sred[w * 3 + 0] = cacc;
        sred[w * 3 + 1] = r;
        sred[w * 3 + 2] = p;
    }
    __syncthreads();
    if (tid == 0) {
        float C = 0.f, R = 0.f, P = 0.f;
        #pragma unroll
        for (int i = 0; i < 8; ++i) {
            C += sred[i * 3 + 0];
            R += sred[i * 3 + 1];
            P += sred[i * 3 + 2];
        }
        parts[b * NBLK + blk] = make_float4(C, R, P, 0.f);
    }
}

__global__ __launch_bounds__(512) void finalize_kernel(
    const float* __restrict__ annots,    // [NB,NM,5]
    const float4* __restrict__ parts,    // [NB*NBLK]
    float* __restrict__ out)
{
    const int tid  = threadIdx.x;
    const int b    = tid >> 6;           // one wave per image (8 waves)
    const int lane = tid & 63;
    __shared__ float simg[NB * 2];

    float C = 0.f, R = 0.f, P = 0.f;
    for (int i = lane; i < NBLK; i += 64) {
        const float4 v = parts[b * NBLK + i];
        C += v.x; R += v.y; P += v.z;
    }
    #pragma unroll
    for (int off = 32; off; off >>= 1) {
        C += __shfl_down(C, off);
        R += __shfl_down(R, off);
        P += __shfl_down(P, off);
    }
    const bool vld = (lane < NM) && (annots[b * NM * 5 + lane * 5 + 4] != -1.0f);
    const unsigned long long m = __ballot(vld);
    if (lane == 0) {
        const bool hv = (m != 0ULL);
        const float d = fmaxf(P, 1.f);
        simg[b * 2 + 0] = hv ? C / d : 0.f;
        simg[b * 2 + 1] = (P > 0.f) ? R / (4.f * d) : 0.f;
    }
    __syncthreads();
    if (tid == 0) {
        float cm = 0.f, rm = 0.f;
        #pragma unroll
        for (int i = 0; i < NB; ++i) {
            cm += simg[i * 2 + 0];
            rm += simg[i * 2 + 1];
        }
        out[0] = cm * (1.f / NB);
        out[1] = rm * (1.f / NB);
    }
}

extern "C" void kernel_launch(void* const* d_in, const int* in_sizes, int n_in,
                              void* d_out, int out_size, void* d_ws, size_t ws_size,
                              hipStream_t stream) {
    const float* cls     = (const float*)d_in[0];  // [NB,NA,NC]
    const float* regs    = (const float*)d_in[1];  // [NB,NA,4]
    const float* anchors = (const float*)d_in[2];  // [1,NA,4]
    const float* annots  = (const float*)d_in[3];  // [NB,NM,5]
    float* out = (float*)d_out;

    float4* parts = (float4*)d_ws;       // NB*NBLK*16 B = 25 KB, fully overwritten

    dim3 g1(NBLK, NB);                   // 1568 blocks
    fused_kernel<<<g1, BLK, 0, stream>>>(cls, regs, anchors, annots, parts);
    finalize_kernel<<<1, 512, 0, stream>>>(annots, parts, out);
}